// Round 10
// baseline (45.181 us; speedup 1.0000x reference)
//
#include <hip/hip_runtime.h>
#include <math.h>

// Problem constants (from reference setup_inputs): B=32, H=W=1024.
constexpr int B = 32;
constexpr int H = 1024;
constexpr int W = 1024;
constexpr int BPB  = 64;              // blocks per batch; also the row stride
constexpr int ROWS = H / BPB;         // 16 rows per block (y = blk + 64*i)
constexpr int NBLK = B * BPB;         // 2048 blocks (exactly CU-resident)
constexpr int NTHREADS = 256;         // 256 threads * float4 = one 1024-px row
constexpr int STR = BPB * W;          // floats per i-step (64 rows)

// Accumulate log2((1+eps) - p): eps folded into the constant, log2 instead of
// ln (the x ln2 is applied once per block), weighted rows use fmaf.
constexpr float KONE = 1.0f + 1e-7f;

__device__ __forceinline__ float row4l2(const float4 v) {
    return __log2f(KONE - v.x) + __log2f(KONE - v.y) +
           __log2f(KONE - v.z) + __log2f(KONE - v.w);
}
__device__ __forceinline__ float row4l2w(const float4 v, const float4 w) {
    float s = w.x * __log2f(KONE - v.x);
    s = fmaf(w.y, __log2f(KONE - v.y), s);
    s = fmaf(w.z, __log2f(KONE - v.z), s);
    s = fmaf(w.w, __log2f(KONE - v.w), s);
    return s;
}

// Single compute kernel: per-block partial of sum_outside log2(KONE - p),
// scaled by (-ln2 / cnt_b / B), block-reduced, then ONE device-scope float
// atomicAdd into out[0]. No second kernel, no ws, no fences (R3's 10x
// regression was the per-block __threadfence L2 writeback, NOT the atomic;
// plain atomicAdd is device-scope at L2 and needs no fence). The 2048
// atomics arrive staggered as blocks retire -> fully hidden.
// out[0] is zeroed each replay by a 4-byte hipMemsetAsync node.
__global__ __launch_bounds__(NTHREADS)
void partial_kernel(const float* __restrict__ pred,
                    const float* __restrict__ bboxes,
                    float* __restrict__ out) {
    const int g   = blockIdx.x;
    const int b   = g >> 6;
    const int blk = g & (BPB - 1);
    const int tid = threadIdx.x;

    // bbox -> integer pixel bounds, exactly matching the reference (scalar).
    const int x1 = max((int)floorf(bboxes[b * 4 + 0] * (float)W), 0);
    const int y1 = max((int)floorf(bboxes[b * 4 + 1] * (float)H), 0);
    const int x2 = min((int)floorf(bboxes[b * 4 + 2] * (float)W), W);
    const int y2 = min((int)floorf(bboxes[b * 4 + 3] * (float)H), H);

    const float area = (float)max(0, y2 - y1) * (float)max(0, x2 - x1);
    const float cnt  = (float)(H * W) - area;
    const float inv  = (cnt > 0.0f) ? (1.0f / fmaxf(cnt, 1.0f)) : 0.0f;

    // inside-row interval in i-space: y1 <= blk+64i < y2
    const int iLo = min(ROWS, max(0, (y1 - blk + 63) >> 6));
    const int iHi = min(ROWS, max(iLo, (y2 - blk + 63) >> 6));

    const float* base = pred + ((size_t)b << 20) + ((size_t)blk << 10);
    const float* pO   = base + (tid << 2);   // this thread's full-row address

    float a0 = 0.0f, a1 = 0.0f, a2 = 0.0f, a3 = 0.0f;

    // --- outside rows before the bbox: i in [0, iLo), 4-deep
    {
        int i = 0;
        for (; i + 4 <= iLo; i += 4) {
            const float4 va = *reinterpret_cast<const float4*>(pO + (size_t)(i + 0) * STR);
            const float4 vb = *reinterpret_cast<const float4*>(pO + (size_t)(i + 1) * STR);
            const float4 vc = *reinterpret_cast<const float4*>(pO + (size_t)(i + 2) * STR);
            const float4 vd = *reinterpret_cast<const float4*>(pO + (size_t)(i + 3) * STR);
            a0 += row4l2(va); a1 += row4l2(vb); a2 += row4l2(vc); a3 += row4l2(vd);
        }
        for (; i < iLo; ++i)
            a0 += row4l2(*reinterpret_cast<const float4*>(pO + (size_t)i * STR));
    }
    // --- outside rows after the bbox: i in [iHi, ROWS), 4-deep
    {
        int i = iHi;
        for (; i + 4 <= ROWS; i += 4) {
            const float4 va = *reinterpret_cast<const float4*>(pO + (size_t)(i + 0) * STR);
            const float4 vb = *reinterpret_cast<const float4*>(pO + (size_t)(i + 1) * STR);
            const float4 vc = *reinterpret_cast<const float4*>(pO + (size_t)(i + 2) * STR);
            const float4 vd = *reinterpret_cast<const float4*>(pO + (size_t)(i + 3) * STR);
            a0 += row4l2(va); a1 += row4l2(vb); a2 += row4l2(vc); a3 += row4l2(vd);
        }
        for (; i < ROWS; ++i)
            a0 += row4l2(*reinterpret_cast<const float4*>(pO + (size_t)i * STR));
    }
    // --- inside rows: compacted columns, constant per-element {0,1} weights
    {
        const int nL   = (x1 + 3) >> 2;     // left-segment float4 count
        const int rS   = x2 >> 2;           // right-segment first float4
        const int nAct = nL + (256 - rS);   // active threads on inside rows
        if (tid < nAct) {
            const int c4 = (tid < nL) ? tid : (rS + tid - nL);
            const int x0 = c4 << 2;
            const float4 w = make_float4(
                (x0 + 0 >= x1 && x0 + 0 < x2) ? 0.0f : 1.0f,
                (x0 + 1 >= x1 && x0 + 1 < x2) ? 0.0f : 1.0f,
                (x0 + 2 >= x1 && x0 + 2 < x2) ? 0.0f : 1.0f,
                (x0 + 3 >= x1 && x0 + 3 < x2) ? 0.0f : 1.0f);
            const float* pI = base + x0;
            int i = iLo;
            for (; i + 2 <= iHi; i += 2) {
                const float4 va = *reinterpret_cast<const float4*>(pI + (size_t)(i + 0) * STR);
                const float4 vb = *reinterpret_cast<const float4*>(pI + (size_t)(i + 1) * STR);
                a0 += row4l2w(va, w);
                a1 += row4l2w(vb, w);
            }
            if (i < iHi)
                a0 += row4l2w(*reinterpret_cast<const float4*>(pI + (size_t)i * STR), w);
        }
    }

    // scale: -ln2 / cnt_b / B  (partial is directly a share of the answer)
    float t = ((a0 + a1) + (a2 + a3)) * (-0.69314718056f / (float)B * inv);

    // block reduction: wave shfl, then LDS across 4 waves
    for (int off = 32; off > 0; off >>= 1)
        t += __shfl_down(t, off, 64);
    __shared__ float s[NTHREADS / 64];
    const int wave = tid >> 6;
    if ((tid & 63) == 0) s[wave] = t;
    __syncthreads();
    if (tid == 0)
        atomicAdd(out, s[0] + s[1] + s[2] + s[3]);
}

extern "C" void kernel_launch(void* const* d_in, const int* in_sizes, int n_in,
                              void* d_out, int out_size, void* d_ws, size_t ws_size,
                              hipStream_t stream) {
    const float* pred   = (const float*)d_in[0];  // (B,1,H,W) f32
    const float* bboxes = (const float*)d_in[1];  // (B,4) f32
    float* out = (float*)d_out;                   // scalar f32

    // zero the accumulator each replay (graph-safe async memset node)
    hipMemsetAsync(d_out, 0, sizeof(float), stream);
    partial_kernel<<<NBLK, NTHREADS, 0, stream>>>(pred, bboxes, out);
}

// Round 11
// 44.715 us; speedup vs baseline: 1.0104x; 1.0104x over previous
//
#include <hip/hip_runtime.h>
#include <math.h>

// ===== MEASUREMENT ROUND =====
// Identical kernels to R9 (best: 20.4us). Only change: K1 is launched THREE
// times (idempotent: ws[g] is a pure function of the inputs, so replaying it
// is deterministic and validation-safe). dur_R11 - dur_R9 = 2 x K1_steady,
// which finally separates {K1 memory tier, K1 fixed cost, K2+gap} -- the
// top-5 rocprof table is saturated by the harness's 75us fills, so K1's own
// duration has been invisible for 10 rounds.

constexpr int B = 32;
constexpr int H = 1024;
constexpr int W = 1024;
constexpr int BPB  = 64;              // blocks per batch; also the row stride
constexpr int ROWS = H / BPB;         // 16 rows per block (y = blk + 64*i)
constexpr int NBLK = B * BPB;         // 2048 blocks (exactly CU-resident)
constexpr int NTHREADS = 256;         // 256 threads * float4 = one 1024-px row
constexpr int STR = BPB * W;          // floats per i-step (64 rows)

constexpr float KONE = 1.0f + 1e-7f;

__device__ __forceinline__ float row4l2(const float4 v) {
    return __log2f(KONE - v.x) + __log2f(KONE - v.y) +
           __log2f(KONE - v.z) + __log2f(KONE - v.w);
}
__device__ __forceinline__ float row4l2w(const float4 v, const float4 w) {
    float s = w.x * __log2f(KONE - v.x);
    s = fmaf(w.y, __log2f(KONE - v.y), s);
    s = fmaf(w.z, __log2f(KONE - v.z), s);
    s = fmaf(w.w, __log2f(KONE - v.w), s);
    return s;
}

__global__ __launch_bounds__(NTHREADS)
void partial_kernel(const float* __restrict__ pred,
                    const float* __restrict__ bboxes,
                    float* __restrict__ ws) {
    const int g   = blockIdx.x;
    const int b   = g >> 6;
    const int blk = g & (BPB - 1);
    const int tid = threadIdx.x;

    const int x1 = max((int)floorf(bboxes[b * 4 + 0] * (float)W), 0);
    const int y1 = max((int)floorf(bboxes[b * 4 + 1] * (float)H), 0);
    const int x2 = min((int)floorf(bboxes[b * 4 + 2] * (float)W), W);
    const int y2 = min((int)floorf(bboxes[b * 4 + 3] * (float)H), H);

    const float area = (float)max(0, y2 - y1) * (float)max(0, x2 - x1);
    const float cnt  = (float)(H * W) - area;
    const float inv  = (cnt > 0.0f) ? (1.0f / fmaxf(cnt, 1.0f)) : 0.0f;

    const int iLo = min(ROWS, max(0, (y1 - blk + 63) >> 6));
    const int iHi = min(ROWS, max(iLo, (y2 - blk + 63) >> 6));

    const float* base = pred + ((size_t)b << 20) + ((size_t)blk << 10);
    const float* pO   = base + (tid << 2);

    float a0 = 0.0f, a1 = 0.0f, a2 = 0.0f, a3 = 0.0f;

    {   // outside rows before the bbox
        int i = 0;
        for (; i + 4 <= iLo; i += 4) {
            const float4 va = *reinterpret_cast<const float4*>(pO + (size_t)(i + 0) * STR);
            const float4 vb = *reinterpret_cast<const float4*>(pO + (size_t)(i + 1) * STR);
            const float4 vc = *reinterpret_cast<const float4*>(pO + (size_t)(i + 2) * STR);
            const float4 vd = *reinterpret_cast<const float4*>(pO + (size_t)(i + 3) * STR);
            a0 += row4l2(va); a1 += row4l2(vb); a2 += row4l2(vc); a3 += row4l2(vd);
        }
        for (; i < iLo; ++i)
            a0 += row4l2(*reinterpret_cast<const float4*>(pO + (size_t)i * STR));
    }
    {   // outside rows after the bbox
        int i = iHi;
        for (; i + 4 <= ROWS; i += 4) {
            const float4 va = *reinterpret_cast<const float4*>(pO + (size_t)(i + 0) * STR);
            const float4 vb = *reinterpret_cast<const float4*>(pO + (size_t)(i + 1) * STR);
            const float4 vc = *reinterpret_cast<const float4*>(pO + (size_t)(i + 2) * STR);
            const float4 vd = *reinterpret_cast<const float4*>(pO + (size_t)(i + 3) * STR);
            a0 += row4l2(va); a1 += row4l2(vb); a2 += row4l2(vc); a3 += row4l2(vd);
        }
        for (; i < ROWS; ++i)
            a0 += row4l2(*reinterpret_cast<const float4*>(pO + (size_t)i * STR));
    }
    {   // inside rows: compacted columns, constant {0,1} weights
        const int nL   = (x1 + 3) >> 2;
        const int rS   = x2 >> 2;
        const int nAct = nL + (256 - rS);
        if (tid < nAct) {
            const int c4 = (tid < nL) ? tid : (rS + tid - nL);
            const int x0 = c4 << 2;
            const float4 w = make_float4(
                (x0 + 0 >= x1 && x0 + 0 < x2) ? 0.0f : 1.0f,
                (x0 + 1 >= x1 && x0 + 1 < x2) ? 0.0f : 1.0f,
                (x0 + 2 >= x1 && x0 + 2 < x2) ? 0.0f : 1.0f,
                (x0 + 3 >= x1 && x0 + 3 < x2) ? 0.0f : 1.0f);
            const float* pI = base + x0;
            int i = iLo;
            for (; i + 2 <= iHi; i += 2) {
                const float4 va = *reinterpret_cast<const float4*>(pI + (size_t)(i + 0) * STR);
                const float4 vb = *reinterpret_cast<const float4*>(pI + (size_t)(i + 1) * STR);
                a0 += row4l2w(va, w);
                a1 += row4l2w(vb, w);
            }
            if (i < iHi)
                a0 += row4l2w(*reinterpret_cast<const float4*>(pI + (size_t)i * STR), w);
        }
    }

    float t = ((a0 + a1) + (a2 + a3)) * (-0.69314718056f * inv);

    for (int off = 32; off > 0; off >>= 1)
        t += __shfl_down(t, off, 64);
    __shared__ float s[NTHREADS / 64];
    const int wave = tid >> 6;
    if ((tid & 63) == 0) s[wave] = t;
    __syncthreads();
    if (tid == 0)
        ws[g] = s[0] + s[1] + s[2] + s[3];
}

__global__ __launch_bounds__(NTHREADS)
void finalize_kernel(const float* __restrict__ ws, float* __restrict__ out) {
    const int tid = threadIdx.x;
    float t = 0.0f;
    const float* p = ws + (size_t)tid * (NBLK / NTHREADS);
#pragma unroll
    for (int i = 0; i < NBLK / NTHREADS; ++i) t += p[i];
    for (int off = 32; off > 0; off >>= 1)
        t += __shfl_down(t, off, 64);
    __shared__ float s[NTHREADS / 64];
    const int wave = tid >> 6;
    if ((tid & 63) == 0) s[wave] = t;
    __syncthreads();
    if (tid == 0)
        out[0] = (s[0] + s[1] + s[2] + s[3]) * (1.0f / (float)B);
}

extern "C" void kernel_launch(void* const* d_in, const int* in_sizes, int n_in,
                              void* d_out, int out_size, void* d_ws, size_t ws_size,
                              hipStream_t stream) {
    const float* pred   = (const float*)d_in[0];  // (B,1,H,W) f32
    const float* bboxes = (const float*)d_in[1];  // (B,4) f32
    float* out = (float*)d_out;                   // scalar f32
    float* ws  = (float*)d_ws;                    // NBLK float partials (8 KB)

    // K1 x3 (idempotent) -- dur delta vs R9 isolates K1's steady-state cost.
    partial_kernel<<<NBLK, NTHREADS, 0, stream>>>(pred, bboxes, ws);
    partial_kernel<<<NBLK, NTHREADS, 0, stream>>>(pred, bboxes, ws);
    partial_kernel<<<NBLK, NTHREADS, 0, stream>>>(pred, bboxes, ws);
    finalize_kernel<<<1, NTHREADS, 0, stream>>>(ws, out);
}

// Round 12
// 20.454 us; speedup vs baseline: 2.2089x; 2.1861x over previous
//
#include <hip/hip_runtime.h>
#include <math.h>

// Problem constants (from reference setup_inputs): B=32, H=W=1024.
constexpr int B = 32;
constexpr int H = 1024;
constexpr int W = 1024;
constexpr int BPB  = 64;              // blocks per batch; also the row stride
constexpr int ROWS = H / BPB;         // 16 rows per block (y = blk + 64*i)
constexpr int NBLK = B * BPB;         // 2048 blocks (exactly CU-resident)
constexpr int NTHREADS = 256;         // 256 threads * float4 = one 1024-px row
constexpr int STR = BPB * W;          // floats per i-step (64 rows)

// K1 verified AT the streaming-BW ceiling (R11 x3 probe: ~11-12us for the
// 78 MB outside footprint ~= 7 TB/s fabric ceiling, same rate L3-hot or
// HBM-cold). This round only trims structural overhead: 4-deep inside loop
// (cold-latency robustness) + vectorized K2.
constexpr float KONE = 1.0f + 1e-7f;

__device__ __forceinline__ float row4l2(const float4 v) {
    return __log2f(KONE - v.x) + __log2f(KONE - v.y) +
           __log2f(KONE - v.z) + __log2f(KONE - v.w);
}
__device__ __forceinline__ float row4l2w(const float4 v, const float4 w) {
    float s = w.x * __log2f(KONE - v.x);
    s = fmaf(w.y, __log2f(KONE - v.y), s);
    s = fmaf(w.z, __log2f(KONE - v.z), s);
    s = fmaf(w.w, __log2f(KONE - v.w), s);
    return s;
}

__global__ __launch_bounds__(NTHREADS)
void partial_kernel(const float* __restrict__ pred,
                    const float* __restrict__ bboxes,
                    float* __restrict__ ws) {
    const int g   = blockIdx.x;
    const int b   = g >> 6;
    const int blk = g & (BPB - 1);
    const int tid = threadIdx.x;

    // bbox -> integer pixel bounds, exactly matching the reference (scalar).
    const int x1 = max((int)floorf(bboxes[b * 4 + 0] * (float)W), 0);
    const int y1 = max((int)floorf(bboxes[b * 4 + 1] * (float)H), 0);
    const int x2 = min((int)floorf(bboxes[b * 4 + 2] * (float)W), W);
    const int y2 = min((int)floorf(bboxes[b * 4 + 3] * (float)H), H);

    const float area = (float)max(0, y2 - y1) * (float)max(0, x2 - x1);
    const float cnt  = (float)(H * W) - area;
    const float inv  = (cnt > 0.0f) ? (1.0f / fmaxf(cnt, 1.0f)) : 0.0f;

    // inside-row interval in i-space: y1 <= blk+64i < y2
    const int iLo = min(ROWS, max(0, (y1 - blk + 63) >> 6));
    const int iHi = min(ROWS, max(iLo, (y2 - blk + 63) >> 6));

    const float* base = pred + ((size_t)b << 20) + ((size_t)blk << 10);
    const float* pO   = base + (tid << 2);

    float a0 = 0.0f, a1 = 0.0f, a2 = 0.0f, a3 = 0.0f;

    {   // outside rows before the bbox: i in [0, iLo), 4-deep
        int i = 0;
        for (; i + 4 <= iLo; i += 4) {
            const float4 va = *reinterpret_cast<const float4*>(pO + (size_t)(i + 0) * STR);
            const float4 vb = *reinterpret_cast<const float4*>(pO + (size_t)(i + 1) * STR);
            const float4 vc = *reinterpret_cast<const float4*>(pO + (size_t)(i + 2) * STR);
            const float4 vd = *reinterpret_cast<const float4*>(pO + (size_t)(i + 3) * STR);
            a0 += row4l2(va); a1 += row4l2(vb); a2 += row4l2(vc); a3 += row4l2(vd);
        }
        for (; i < iLo; ++i)
            a0 += row4l2(*reinterpret_cast<const float4*>(pO + (size_t)i * STR));
    }
    {   // outside rows after the bbox: i in [iHi, ROWS), 4-deep
        int i = iHi;
        for (; i + 4 <= ROWS; i += 4) {
            const float4 va = *reinterpret_cast<const float4*>(pO + (size_t)(i + 0) * STR);
            const float4 vb = *reinterpret_cast<const float4*>(pO + (size_t)(i + 1) * STR);
            const float4 vc = *reinterpret_cast<const float4*>(pO + (size_t)(i + 2) * STR);
            const float4 vd = *reinterpret_cast<const float4*>(pO + (size_t)(i + 3) * STR);
            a0 += row4l2(va); a1 += row4l2(vb); a2 += row4l2(vc); a3 += row4l2(vd);
        }
        for (; i < ROWS; ++i)
            a0 += row4l2(*reinterpret_cast<const float4*>(pO + (size_t)i * STR));
    }
    {   // inside rows: compacted columns, constant {0,1} weights, 4-deep
        const int nL   = (x1 + 3) >> 2;
        const int rS   = x2 >> 2;
        const int nAct = nL + (256 - rS);
        if (tid < nAct) {
            const int c4 = (tid < nL) ? tid : (rS + tid - nL);
            const int x0 = c4 << 2;
            const float4 w = make_float4(
                (x0 + 0 >= x1 && x0 + 0 < x2) ? 0.0f : 1.0f,
                (x0 + 1 >= x1 && x0 + 1 < x2) ? 0.0f : 1.0f,
                (x0 + 2 >= x1 && x0 + 2 < x2) ? 0.0f : 1.0f,
                (x0 + 3 >= x1 && x0 + 3 < x2) ? 0.0f : 1.0f);
            const float* pI = base + x0;
            int i = iLo;
            for (; i + 4 <= iHi; i += 4) {
                const float4 va = *reinterpret_cast<const float4*>(pI + (size_t)(i + 0) * STR);
                const float4 vb = *reinterpret_cast<const float4*>(pI + (size_t)(i + 1) * STR);
                const float4 vc = *reinterpret_cast<const float4*>(pI + (size_t)(i + 2) * STR);
                const float4 vd = *reinterpret_cast<const float4*>(pI + (size_t)(i + 3) * STR);
                a0 += row4l2w(va, w); a1 += row4l2w(vb, w);
                a2 += row4l2w(vc, w); a3 += row4l2w(vd, w);
            }
            for (; i < iHi; ++i)
                a0 += row4l2w(*reinterpret_cast<const float4*>(pI + (size_t)i * STR), w);
        }
    }

    // pre-scale: -ln2 / cnt_b  (makes partials batch-agnostic)
    float t = ((a0 + a1) + (a2 + a3)) * (-0.69314718056f * inv);

    // block reduction: wave shfl, then LDS across 4 waves
    for (int off = 32; off > 0; off >>= 1)
        t += __shfl_down(t, off, 64);
    __shared__ float s[NTHREADS / 64];
    const int wave = tid >> 6;
    if ((tid & 63) == 0) s[wave] = t;
    __syncthreads();
    if (tid == 0)
        ws[g] = s[0] + s[1] + s[2] + s[3];
}

// Kernel 2: one block, vectorized fixed-order sum of the 2048 partials
// (256 threads x 2 float4), deterministic tree, writes the scalar mean.
__global__ __launch_bounds__(NTHREADS)
void finalize_kernel(const float* __restrict__ ws, float* __restrict__ out) {
    const int tid = threadIdx.x;
    const float4 v0 = *reinterpret_cast<const float4*>(ws + (size_t)tid * 8);
    const float4 v1 = *reinterpret_cast<const float4*>(ws + (size_t)tid * 8 + 4);
    float t = ((v0.x + v0.y) + (v0.z + v0.w)) + ((v1.x + v1.y) + (v1.z + v1.w));
    for (int off = 32; off > 0; off >>= 1)
        t += __shfl_down(t, off, 64);
    __shared__ float s[NTHREADS / 64];
    const int wave = tid >> 6;
    if ((tid & 63) == 0) s[wave] = t;
    __syncthreads();
    if (tid == 0)
        out[0] = (s[0] + s[1] + s[2] + s[3]) * (1.0f / (float)B);
}

extern "C" void kernel_launch(void* const* d_in, const int* in_sizes, int n_in,
                              void* d_out, int out_size, void* d_ws, size_t ws_size,
                              hipStream_t stream) {
    const float* pred   = (const float*)d_in[0];  // (B,1,H,W) f32
    const float* bboxes = (const float*)d_in[1];  // (B,4) f32
    float* out = (float*)d_out;                   // scalar f32
    float* ws  = (float*)d_ws;                    // NBLK float partials (8 KB)

    partial_kernel<<<NBLK, NTHREADS, 0, stream>>>(pred, bboxes, ws);
    finalize_kernel<<<1, NTHREADS, 0, stream>>>(ws, out);
}